// Round 10
// baseline (188.647 us; speedup 1.0000x reference)
//
#include <hip/hip_runtime.h>

using u16 = unsigned short;
typedef __attribute__((ext_vector_type(4))) float f32x4;
typedef __attribute__((ext_vector_type(8))) short s16x8;
typedef __attribute__((ext_vector_type(4))) unsigned short u16x4;

#define MFMA(a, b, c) __builtin_amdgcn_mfma_f32_16x16x32_bf16((a), (b), (c), 0, 0, 0)

__device__ __forceinline__ u16 f2bf(float f) {
  unsigned u = __float_as_uint(f);
  u += 0x7fff + ((u >> 16) & 1);
  return (u16)(u >> 16);
}
__device__ __forceinline__ float bf2f(u16 h) {
  return __uint_as_float((unsigned)h << 16);
}

// ---------------------------------------------------------------- transpose+convert all weights, one launch
struct TrArgs {
  const float* src[8];
  u16* dst[8];
  int K[8], N[8];
  int tstart[9];
};
__global__ __launch_bounds__(256) void tr_kernel(TrArgs a) {
  __shared__ float t[32][33];
  int tile = blockIdx.x;
  int m = 0;
  while (tile >= a.tstart[m + 1]) m++;
  int ti = tile - a.tstart[m];
  int K = a.K[m], N = a.N[m];
  int ntn = N >> 5;
  int tk = ti / ntn;
  int k0 = tk << 5, n0 = (ti - tk * ntn) << 5;
  int r = threadIdx.x >> 3, c4 = (threadIdx.x & 7) << 2;
  const float* s = a.src[m] + (size_t)(k0 + r) * N + n0 + c4;
  float4 v = *(const float4*)s;
  t[r][c4 + 0] = v.x;
  t[r][c4 + 1] = v.y;
  t[r][c4 + 2] = v.z;
  t[r][c4 + 3] = v.w;
  __syncthreads();
  size_t o = (size_t)(n0 + r) * K + k0 + c4;
  u16* d = a.dst[m];
#pragma unroll
  for (int j = 0; j < 4; j++) d[o + j] = f2bf(t[c4 + j][r]);
}

// ---------------------------------------------------------------- LayerNorm (W=256), batched over branches
struct LN1Args {
  const float* x[3];
  const float* g[3];
  const float* b[3];
  u16* out;  // [3][4096][256]
};
__global__ __launch_bounds__(256) void ln1_kernel(LN1Args a) {
  int lane = threadIdx.x & 63, wid = threadIdx.x >> 6;
  int row = blockIdx.x * 4 + wid;
  int br = blockIdx.y;
  const float* xp = a.x[br] + (size_t)row * 256;
  float v[4], s = 0.f, s2 = 0.f;
#pragma unroll
  for (int j = 0; j < 4; j++) {
    v[j] = xp[lane + 64 * j];
    s += v[j];
    s2 += v[j] * v[j];
  }
#pragma unroll
  for (int m = 32; m; m >>= 1) {
    s += __shfl_xor(s, m);
    s2 += __shfl_xor(s2, m);
  }
  float mean = s * (1.f / 256.f);
  float rstd = rsqrtf(s2 * (1.f / 256.f) - mean * mean + 1e-5f);
  u16* o = a.out + (size_t)br * 1048576 + (size_t)row * 256;
#pragma unroll
  for (int j = 0; j < 4; j++) {
    int c = lane + 64 * j;
    o[c] = f2bf((v[j] - mean) * rstd * a.g[br][c] + a.b[br][c]);
  }
}

// ---------------------------------------------------------------- LayerNorm2 (W=768) -> bf16
__global__ __launch_bounds__(256) void ln2_kernel(const float* xc, const float* g, const float* b,
                                                  u16* oh) {
  int lane = threadIdx.x & 63, wid = threadIdx.x >> 6;
  int row = blockIdx.x * 4 + wid;
  float v[12], s = 0.f, s2 = 0.f;
#pragma unroll
  for (int j = 0; j < 12; j++) {
    int c = lane + 64 * j;
    v[j] = xc[(size_t)(c >> 8) * 1048576 + (size_t)row * 256 + (c & 255)];
    s += v[j];
    s2 += v[j] * v[j];
  }
#pragma unroll
  for (int m = 32; m; m >>= 1) {
    s += __shfl_xor(s, m);
    s2 += __shfl_xor(s2, m);
  }
  float mean = s * (1.f / 768.f);
  float rstd = rsqrtf(s2 * (1.f / 768.f) - mean * mean + 1e-5f);
#pragma unroll
  for (int j = 0; j < 12; j++) {
    int c = lane + 64 * j;
    oh[(size_t)row * 768 + c] = f2bf((v[j] - mean) * rstd * g[c] + b[c]);
  }
}

// ---------------------------------------------------------------- sum NSPLIT KV partials + RMSNorm -> aoN
struct RmsArgs {
  const u16* ao4;
  const float* sc[3];
  u16* aoN;
  int brAo, brAoN;  // per-branch element strides (0 in serial mode)
};
template <int NSPLIT>
__global__ __launch_bounds__(256) void rms_sum_kernel(RmsArgs a) {
  int lane = threadIdx.x & 63, wid = threadIdx.x >> 6;
  int row = blockIdx.x * 4 + wid;
  int br = blockIdx.y;
  const u16* base = a.ao4 + (size_t)br * a.brAo + (size_t)row * 512;
  float v[8], s2 = 0.f;
#pragma unroll
  for (int j = 0; j < 8; j++) {
    int c = lane + 64 * j;
    float acc = 0.f;
#pragma unroll
    for (int s = 0; s < NSPLIT; s++) acc += bf2f(base[(size_t)s * 2097152 + c]);
    v[j] = acc;
    s2 += v[j] * v[j];
  }
#pragma unroll
  for (int m = 32; m; m >>= 1) s2 += __shfl_xor(s2, m);
  float inv = 1.f / (sqrtf(s2) * 0.044194173824159216f + 1e-8f);  // *512^-0.5
  const float* sc = a.sc[br];
  u16* o = a.aoN + (size_t)br * a.brAoN + (size_t)row * 512;
#pragma unroll
  for (int j = 0; j < 8; j++) {
    int c = lane + 64 * j;
    o[c] = f2bf(v[j] * inv * sc[c]);
  }
}

// ---------------------------------------------------------------- QKV GEMM 128x128 (M=4096,N=1536,K=256)
// q,k written natural [bh][n][64] (q scaled 0.125); v written TRANSPOSED [bh][d=64][n=2048].
struct GemmQkvArgs {
  const u16* A;
  const u16* Bt;
  u16 *q, *k, *v;
};
__global__ __launch_bounds__(256) void gemmqkv_kernel(GemmQkvArgs g) {
  __shared__ u16 As[128][40];
  __shared__ u16 Bs[128][40];
  const int tid = threadIdx.x;
  const int lane = tid & 63, wid = tid >> 6;
  const int wm = wid >> 1, wn = wid & 1;
  const int lr = lane & 15, lg = lane >> 4;
  const int m0 = blockIdx.y * 128, n0 = blockIdx.x * 128;
  const int z = blockIdx.z;
  const int K = 256;
  f32x4 acc[4][4] = {};
  const int sr = tid >> 1, sh = (tid & 1) << 4;
  const u16* ga = g.A + (size_t)z * 1048576 + (size_t)(m0 + sr) * K + sh;
  const u16* gb = g.Bt + (size_t)z * 393216 + (size_t)(n0 + sr) * K + sh;
  for (int k0 = 0; k0 < K; k0 += 32) {
    s16x8 a0 = *(const s16x8*)(ga + k0);
    s16x8 a1 = *(const s16x8*)(ga + k0 + 8);
    s16x8 b0 = *(const s16x8*)(gb + k0);
    s16x8 b1 = *(const s16x8*)(gb + k0 + 8);
    __syncthreads();
    *(s16x8*)&As[sr][sh] = a0;
    *(s16x8*)&As[sr][sh + 8] = a1;
    *(s16x8*)&Bs[sr][sh] = b0;
    *(s16x8*)&Bs[sr][sh + 8] = b1;
    __syncthreads();
    s16x8 af[4], bfr[4];
#pragma unroll
    for (int mt = 0; mt < 4; mt++) af[mt] = *(const s16x8*)&As[wm * 64 + mt * 16 + lr][lg * 8];
#pragma unroll
    for (int nt = 0; nt < 4; nt++) bfr[nt] = *(const s16x8*)&Bs[wn * 64 + nt * 16 + lr][lg * 8];
#pragma unroll
    for (int mt = 0; mt < 4; mt++)
#pragma unroll
      for (int nt = 0; nt < 4; nt++) acc[mt][nt] = MFMA(af[mt], bfr[nt], acc[mt][nt]);
  }
  const int seg = n0 >> 9;
  if (seg == 2) {
    u16* vz = g.v + (size_t)z * 2097152;
#pragma unroll
    for (int mt = 0; mt < 4; mt++) {
      int nbase = m0 + wm * 64 + mt * 16 + lg * 4;
      int b = nbase >> 11, n = nbase & 2047;
#pragma unroll
      for (int nt = 0; nt < 4; nt++) {
        int col = n0 + wn * 64 + nt * 16 + lr;
        int hh = (col >> 6) & 7, d = col & 63;
        u16x4 w;
#pragma unroll
        for (int r = 0; r < 4; r++) w[r] = f2bf(acc[mt][nt][r]);
        *(u16x4*)(vz + (size_t)((b << 3) + hh) * 131072 + (size_t)d * 2048 + n) = w;
      }
    }
  } else {
    u16* dst = (seg == 0 ? g.q : g.k) + (size_t)z * 2097152;
    const float scv = (seg == 0) ? 0.125f : 1.0f;
#pragma unroll
    for (int mt = 0; mt < 4; mt++)
#pragma unroll
      for (int nt = 0; nt < 4; nt++)
#pragma unroll
        for (int r = 0; r < 4; r++) {
          int row = m0 + wm * 64 + mt * 16 + lg * 4 + r;
          int col = n0 + wn * 64 + nt * 16 + lr;
          int hh = (col >> 6) & 7, d = col & 63;
          int b = row >> 11, n = row & 2047;
          dst[(size_t)((b << 3) + hh) * 131072 + (size_t)n * 64 + d] = f2bf(acc[mt][nt][r] * scv);
        }
  }
}

// ---------------------------------------------------------------- WO GEMM 64x64 tile (+bias+residual->fp32)
struct Gemm64Args {
  const u16* A;   // [4096][512]
  const u16* Bt;  // [256][512]
  const float* bias[3];
  const float* res[3];
  float* outf;
  int aStr, btStr, outStr;
};
__global__ __launch_bounds__(256) void gemm64_kernel(Gemm64Args g) {
  __shared__ u16 As[64][40];
  __shared__ u16 Bs[64][40];
  const int tid = threadIdx.x;
  const int lane = tid & 63, wid = tid >> 6;
  const int wm = wid >> 1, wn = wid & 1;
  const int lr = lane & 15, lg = lane >> 4;
  const int m0 = blockIdx.y * 64, n0 = blockIdx.x * 64;
  const int z = blockIdx.z;
  const int K = 512;
  f32x4 acc[2][2] = {};
  const int sr = tid >> 2, sh8 = (tid & 3) << 3;
  const u16* ga = g.A + (size_t)z * g.aStr + (size_t)(m0 + sr) * K + sh8;
  const u16* gb = g.Bt + (size_t)z * g.btStr + (size_t)(n0 + sr) * K + sh8;
  for (int k0 = 0; k0 < K; k0 += 32) {
    s16x8 a0 = *(const s16x8*)(ga + k0);
    s16x8 b0 = *(const s16x8*)(gb + k0);
    __syncthreads();
    *(s16x8*)&As[sr][sh8] = a0;
    *(s16x8*)&Bs[sr][sh8] = b0;
    __syncthreads();
    s16x8 af[2], bfr[2];
#pragma unroll
    for (int mt = 0; mt < 2; mt++) af[mt] = *(const s16x8*)&As[wm * 32 + mt * 16 + lr][lg * 8];
#pragma unroll
    for (int nt = 0; nt < 2; nt++) bfr[nt] = *(const s16x8*)&Bs[wn * 32 + nt * 16 + lr][lg * 8];
#pragma unroll
    for (int mt = 0; mt < 2; mt++)
#pragma unroll
      for (int nt = 0; nt < 2; nt++) acc[mt][nt] = MFMA(af[mt], bfr[nt], acc[mt][nt]);
  }
  float* of = g.outf + (size_t)z * g.outStr;
#pragma unroll
  for (int mt = 0; mt < 2; mt++)
#pragma unroll
    for (int nt = 0; nt < 2; nt++)
#pragma unroll
      for (int r = 0; r < 4; r++) {
        int row = m0 + wm * 32 + mt * 16 + lg * 4 + r;
        int col = n0 + wn * 32 + nt * 16 + lr;
        float val = acc[mt][nt][r] + g.bias[z][col] + g.res[z][(size_t)row * 256 + col];
        of[(size_t)row * 256 + col] = val;
      }
}

// ---------------------------------------------------------------- MLP GEMM, 128x64 tile, single bf16 term
struct GemmMlpArgs {
  const u16 *A, *Bt;
  int K;
  const float* bias;
  u16* oh;      // EPI 0
  float* outf;  // EPI 1
};
template <int EPI>
__global__ __launch_bounds__(256) void gemmmlp_kernel(GemmMlpArgs g) {
  __shared__ u16 As[128][40], Bs[64][40];
  const int tid = threadIdx.x;
  const int lane = tid & 63, wid = tid >> 6;
  const int wm = wid >> 1, wn = wid & 1;
  const int lr = lane & 15, lg = lane >> 4;
  const int m0 = blockIdx.y * 128, n0 = blockIdx.x * 64;
  const int K = g.K;
  f32x4 acc[4][2] = {};
  const int sra = tid >> 1, sha = (tid & 1) << 4;
  const int srb = tid >> 2, shb = (tid & 3) << 3;
  const u16* ga = g.A + (size_t)(m0 + sra) * K + sha;
  const u16* gb = g.Bt + (size_t)(n0 + srb) * K + shb;
  for (int k0 = 0; k0 < K; k0 += 32) {
    s16x8 a0 = *(const s16x8*)(ga + k0);
    s16x8 a1 = *(const s16x8*)(ga + k0 + 8);
    s16x8 b0 = *(const s16x8*)(gb + k0);
    __syncthreads();
    *(s16x8*)&As[sra][sha] = a0;
    *(s16x8*)&As[sra][sha + 8] = a1;
    *(s16x8*)&Bs[srb][shb] = b0;
    __syncthreads();
    s16x8 af[4], bfr[2];
#pragma unroll
    for (int mt = 0; mt < 4; mt++) af[mt] = *(const s16x8*)&As[wm * 64 + mt * 16 + lr][lg * 8];
#pragma unroll
    for (int nt = 0; nt < 2; nt++) bfr[nt] = *(const s16x8*)&Bs[wn * 32 + nt * 16 + lr][lg * 8];
#pragma unroll
    for (int mt = 0; mt < 4; mt++)
#pragma unroll
      for (int nt = 0; nt < 2; nt++) acc[mt][nt] = MFMA(af[mt], bfr[nt], acc[mt][nt]);
  }
#pragma unroll
  for (int mt = 0; mt < 4; mt++)
#pragma unroll
    for (int nt = 0; nt < 2; nt++)
#pragma unroll
      for (int r = 0; r < 4; r++) {
        int row = m0 + wm * 64 + mt * 16 + lg * 4 + r;
        int col = n0 + wn * 32 + nt * 16 + lr;
        float val = acc[mt][nt][r] + g.bias[col];
        if (EPI == 0) {
          float ge = 0.5f * val * (1.0f + erff(val * 0.70710678118654752f));
          g.oh[(size_t)row * 1024 + col] = f2bf(ge);
        } else {
          int chunk = col >> 8, cc = col & 255;
          float* p = g.outf + (size_t)chunk * 1048576 + (size_t)row * 256 + cc;
          *p = val + *p;
        }
      }
}

// ---------------------------------------------------------------- ReLU attention (R8-proven math)
// QBLK=128 (4 waves x 32 q). 1-D XCD-swizzled grid: L = qb*NG + g, g=(br,bh,sp); NG%8==0 so all
// 16 qb-blocks of one (br,bh,sp) group land on one XCD -> K/V slice L2-resident.
// LDS overlay: Ps[128][72] rows 0-63 double as Ks (extra barrier between S-reads and P-writes).
template <int NSPLIT, int NBR>
__global__ __launch_bounds__(256) void attn_kernel(const u16* q, const u16* k, const u16* vT,
                                                   u16* ao4, int brQkv, int brAo) {
  __shared__ u16 Pool[128][72];  // Ps; rows 0-63 double as Ks [kv][d]
  __shared__ u16 Vt[64][72];     // [d][kv]
  const int tid = threadIdx.x;
  const int lane = tid & 63, wid = tid >> 6;
  const int lr = lane & 15, lg = lane >> 4;
  const int NG = NBR * 16 * NSPLIT;
  const int L = blockIdx.x;
  const int qb = L / NG, g = L % NG;
  const int br = g / (16 * NSPLIT);
  const int rest = g % (16 * NSPLIT);
  const int bh = rest / NSPLIT, sp = rest % NSPLIT;
  const size_t boff = (size_t)br * brQkv + (size_t)bh * 131072;
  const u16* qp = q + boff;
  const u16* kp = k + boff;
  const u16* vp = vT + boff;
  s16x8 qf[2][2];
#pragma unroll
  for (int mt = 0; mt < 2; mt++)
#pragma unroll
    for (int ks = 0; ks < 2; ks++)
      qf[mt][ks] = *(const s16x8*)(qp + (size_t)(qb * 128 + wid * 32 + mt * 16 + lr) * 64 + ks * 32 + lg * 8);
  f32x4 oacc[2][4] = {};
  const int sr = tid >> 2, sc = (tid & 3) << 4;
  const u16* kg = kp + sr * 64 + sc;    // K rows [kv][d]
  const u16* vg = vp + sr * 2048 + sc;  // vT rows [d][n]
  const int TPS = 32 / NSPLIT;
  const int ktL = sp * TPS, ktH = ktL + TPS;
  s16x8 kv0 = *(const s16x8*)(kg + ktL * 4096);
  s16x8 kv1 = *(const s16x8*)(kg + ktL * 4096 + 8);
  s16x8 vv0 = *(const s16x8*)(vg + ktL * 64);
  s16x8 vv1 = *(const s16x8*)(vg + ktL * 64 + 8);
  for (int kt = ktL; kt < ktH; kt++) {
    __syncthreads();  // prev iter's Ps/Vt reads done -> safe to overwrite Ks(=Pool rows 0-63)/Vt
    *(s16x8*)&Pool[sr][sc] = kv0;
    *(s16x8*)&Pool[sr][sc + 8] = kv1;
    *(s16x8*)&Vt[sr][sc] = vv0;
    *(s16x8*)&Vt[sr][sc + 8] = vv1;
    __syncthreads();
    const int nx = (kt + 1 < ktH) ? kt + 1 : kt;
    kv0 = *(const s16x8*)(kg + nx * 4096);
    kv1 = *(const s16x8*)(kg + nx * 4096 + 8);
    vv0 = *(const s16x8*)(vg + nx * 64);
    vv1 = *(const s16x8*)(vg + nx * 64 + 8);
    // S = Q K^T (reads Pool rows 0-63 as Ks)
    f32x4 sacc[2][4] = {};
#pragma unroll
    for (int nt = 0; nt < 4; nt++)
#pragma unroll
      for (int ks = 0; ks < 2; ks++) {
        s16x8 kf = *(const s16x8*)&Pool[nt * 16 + lr][ks * 32 + lg * 8];
        sacc[0][nt] = MFMA(qf[0][ks], kf, sacc[0][nt]);
        sacc[1][nt] = MFMA(qf[1][ks], kf, sacc[1][nt]);
      }
    __syncthreads();  // all waves' Ks reads done before P writes clobber Pool
    // P = relu(S) -> Pool (own 32 rows)
#pragma unroll
    for (int mt = 0; mt < 2; mt++)
#pragma unroll
      for (int nt = 0; nt < 4; nt++)
#pragma unroll
        for (int r = 0; r < 4; r++) {
          float s = sacc[mt][nt][r];
          Pool[wid * 32 + mt * 16 + lg * 4 + r][nt * 16 + lr] = f2bf(s > 0.f ? s : 0.f);
        }
    // O += P V (reads own-wave P rows: same-wave DS ordering; Vt barrier-protected above)
#pragma unroll
    for (int ks = 0; ks < 2; ks++) {
      s16x8 pa0 = *(const s16x8*)&Pool[wid * 32 + lr][ks * 32 + lg * 8];
      s16x8 pa1 = *(const s16x8*)&Pool[wid * 32 + 16 + lr][ks * 32 + lg * 8];
#pragma unroll
      for (int nt = 0; nt < 4; nt++) {
        s16x8 vf = *(const s16x8*)&Vt[nt * 16 + lr][ks * 32 + lg * 8];
        oacc[0][nt] = MFMA(pa0, vf, oacc[0][nt]);
        oacc[1][nt] = MFMA(pa1, vf, oacc[1][nt]);
      }
    }
  }
  u16* aop = ao4 + (size_t)br * brAo + (size_t)sp * 2097152;
  const int b = bh >> 3, h = bh & 7;
#pragma unroll
  for (int mt = 0; mt < 2; mt++)
#pragma unroll
    for (int nt = 0; nt < 4; nt++)
#pragma unroll
      for (int r = 0; r < 4; r++) {
        int qrow = qb * 128 + wid * 32 + mt * 16 + lg * 4 + r;
        aop[(size_t)(b * 2048 + qrow) * 512 + h * 64 + nt * 16 + lr] = f2bf(oacc[mt][nt][r]);
      }
}

// ----------------------------------------------------------------
extern "C" void kernel_launch(void* const* d_in, const int* in_sizes, int n_in,
                              void* d_out, int out_size, void* d_ws, size_t ws_size,
                              hipStream_t stream) {
  const float* X[3] = {(const float*)d_in[0], (const float*)d_in[1], (const float*)d_in[2]};
  const float* G1[3] = {(const float*)d_in[3], (const float*)d_in[9], (const float*)d_in[15]};
  const float* B1[3] = {(const float*)d_in[4], (const float*)d_in[10], (const float*)d_in[16]};
  const float* WQKV[3] = {(const float*)d_in[5], (const float*)d_in[11], (const float*)d_in[17]};
  const float* RMS[3] = {(const float*)d_in[6], (const float*)d_in[12], (const float*)d_in[18]};
  const float* WO[3] = {(const float*)d_in[7], (const float*)d_in[13], (const float*)d_in[19]};
  const float* BO[3] = {(const float*)d_in[8], (const float*)d_in[14], (const float*)d_in[20]};
  const float* G2 = (const float*)d_in[21];
  const float* B2 = (const float*)d_in[22];
  const float* WFC1 = (const float*)d_in[23];
  const float* BFC1 = (const float*)d_in[24];
  const float* WFC2 = (const float*)d_in[25];
  const float* BFC2 = (const float*)d_in[26];
  float* dout = (float*)d_out;
  u16* W = (u16*)d_ws;

  const bool batched = ws_size >= 88080384ULL;  // 44,040,192 u16 elems

  // 1) all weight transposes, one launch (shared)
  u16* wqkvT = W;            // [3][1536][256]
  u16* woT = W + 1179648;    // [3][256][512]
  u16* fc1T = W + 1572864;   // [1024][768]
  u16* fc2T = W + 2359296;   // [768][1024]
  u16* xn = W + 3145728;     // [3][4096][256]   .. 6,291,456
  TrArgs ta;
  const float* srcs[8] = {WQKV[0], WQKV[1], WQKV[2], WO[0], WO[1], WO[2], WFC1, WFC2};
  u16* dsts[8] = {wqkvT, wqkvT + 393216, wqkvT + 786432, woT, woT + 131072, woT + 262144, fc1T, fc2T};
  int Ks_[8] = {256, 256, 256, 512, 512, 512, 768, 1024};
  int Ns_[8] = {1536, 1536, 1536, 256, 256, 256, 1024, 768};
  int tst[9] = {0, 384, 768, 1152, 1280, 1408, 1536, 2304, 3072};
  for (int i = 0; i < 8; i++) {
    ta.src[i] = srcs[i];
    ta.dst[i] = dsts[i];
    ta.K[i] = Ks_[i];
    ta.N[i] = Ns_[i];
    ta.tstart[i] = tst[i];
  }
  ta.tstart[8] = tst[8];
  hipLaunchKernelGGL(tr_kernel, dim3(3072), dim3(256), 0, stream, ta);

  // 2) LN1 (shared)
  LN1Args la;
  for (int i = 0; i < 3; i++) {
    la.x[i] = X[i];
    la.g[i] = G1[i];
    la.b[i] = B1[i];
  }
  la.out = xn;
  hipLaunchKernelGGL(ln1_kernel, dim3(1024, 3), dim3(256), 0, stream, la);

  u16 *ln2b, *hbuf;

  if (batched) {
    u16* qall = W + 6291456;
    u16* kall = W + 12582912;
    u16* vall = W + 18874368;
    u16* ao4 = W + 25165824;   // [3][2][4096][512]
    u16* aoN = W + 37748736;   // [3][4096][512]
    ln2b = W + 6291456;
    hbuf = W + 9437184;

    GemmQkvArgs gq = {xn, wqkvT, qall, kall, vall};
    hipLaunchKernelGGL(gemmqkv_kernel, dim3(12, 32, 3), dim3(256), 0, stream, gq);

    hipLaunchKernelGGL((attn_kernel<2, 3>), dim3(1536), dim3(256), 0, stream,
                       qall, kall, vall, ao4, 2097152, 4194304);

    RmsArgs ra;
    ra.ao4 = ao4;
    for (int i = 0; i < 3; i++) ra.sc[i] = RMS[i];
    ra.aoN = aoN;
    ra.brAo = 4194304;
    ra.brAoN = 2097152;
    hipLaunchKernelGGL(rms_sum_kernel<2>, dim3(1024, 3), dim3(256), 0, stream, ra);

    Gemm64Args gw;
    gw.A = aoN;
    gw.Bt = woT;
    for (int i = 0; i < 3; i++) {
      gw.bias[i] = BO[i];
      gw.res[i] = X[i];
    }
    gw.outf = dout;
    gw.aStr = 2097152;
    gw.btStr = 131072;
    gw.outStr = 1048576;
    hipLaunchKernelGGL(gemm64_kernel, dim3(4, 64, 3), dim3(256), 0, stream, gw);
  } else {
    // Serial fallback (R8-proven, peak 44 MiB)
    u16* qz = W + 6291456;
    u16* kz = W + 8388608;
    u16* vz = W + 10485760;
    u16* ao4 = W + 12582912;  // [4][4096][512]
    u16* aoN = W + 20971520;
    ln2b = W + 6291456;
    hbuf = W + 9437184;

    for (int z = 0; z < 3; z++) {
      GemmQkvArgs gq = {xn + (size_t)z * 1048576, wqkvT + (size_t)z * 393216, qz, kz, vz};
      hipLaunchKernelGGL(gemmqkv_kernel, dim3(12, 32, 1), dim3(256), 0, stream, gq);

      hipLaunchKernelGGL((attn_kernel<4, 1>), dim3(1024), dim3(256), 0, stream,
                         qz, kz, vz, ao4, 0, 0);

      RmsArgs ra;
      ra.ao4 = ao4;
      ra.sc[0] = RMS[z];
      ra.sc[1] = RMS[z];
      ra.sc[2] = RMS[z];
      ra.aoN = aoN;
      ra.brAo = 0;
      ra.brAoN = 0;
      hipLaunchKernelGGL(rms_sum_kernel<4>, dim3(1024, 1), dim3(256), 0, stream, ra);

      Gemm64Args gw;
      gw.A = aoN;
      gw.Bt = woT + (size_t)z * 131072;
      for (int i = 0; i < 3; i++) {
        gw.bias[i] = BO[z];
        gw.res[i] = X[z];
      }
      gw.outf = dout + (size_t)z * 1048576;
      gw.aStr = 0;
      gw.btStr = 0;
      gw.outStr = 0;
      hipLaunchKernelGGL(gemm64_kernel, dim3(4, 64, 1), dim3(256), 0, stream, gw);
    }
  }

  // 4) LN2 -> bf16
  hipLaunchKernelGGL(ln2_kernel, dim3(1024), dim3(256), 0, stream, dout, G2, B2, ln2b);

  // 5) FC1 (M=4096,N=1024,K=768) + gelu -> hbuf
  GemmMlpArgs g1 = {};
  g1.A = ln2b;
  g1.Bt = fc1T;
  g1.K = 768;
  g1.bias = BFC1;
  g1.oh = hbuf;
  hipLaunchKernelGGL(gemmmlp_kernel<0>, dim3(16, 32), dim3(256), 0, stream, g1);

  // 6) FC2 (M=4096,N=768,K=1024) + bias + residual RMW on d_out
  GemmMlpArgs g2 = {};
  g2.A = hbuf;
  g2.Bt = fc2T;
  g2.K = 1024;
  g2.bias = BFC2;
  g2.outf = dout;
  hipLaunchKernelGGL(gemmmlp_kernel<1>, dim3(12, 32), dim3(256), 0, stream, g2);
}

// Round 11
// 180.401 us; speedup vs baseline: 1.0457x; 1.0457x over previous
//
#include <hip/hip_runtime.h>

using u16 = unsigned short;
typedef __attribute__((ext_vector_type(4))) float f32x4;
typedef __attribute__((ext_vector_type(16))) float f32x16;
typedef __attribute__((ext_vector_type(8))) short s16x8;
typedef __attribute__((ext_vector_type(4))) unsigned short u16x4;

#define MFMA(a, b, c) __builtin_amdgcn_mfma_f32_16x16x32_bf16((a), (b), (c), 0, 0, 0)
#define MFMA32(a, b, c) __builtin_amdgcn_mfma_f32_32x32x16_bf16((a), (b), (c), 0, 0, 0)

__device__ __forceinline__ u16 f2bf(float f) {
  unsigned u = __float_as_uint(f);
  u += 0x7fff + ((u >> 16) & 1);
  return (u16)(u >> 16);
}
__device__ __forceinline__ float bf2f(u16 h) {
  return __uint_as_float((unsigned)h << 16);
}

// ---------------------------------------------------------------- transpose+convert all weights, one launch
struct TrArgs {
  const float* src[8];
  u16* dst[8];
  int K[8], N[8];
  int tstart[9];
};
__global__ __launch_bounds__(256) void tr_kernel(TrArgs a) {
  __shared__ float t[32][33];
  int tile = blockIdx.x;
  int m = 0;
  while (tile >= a.tstart[m + 1]) m++;
  int ti = tile - a.tstart[m];
  int K = a.K[m], N = a.N[m];
  int ntn = N >> 5;
  int tk = ti / ntn;
  int k0 = tk << 5, n0 = (ti - tk * ntn) << 5;
  int r = threadIdx.x >> 3, c4 = (threadIdx.x & 7) << 2;
  const float* s = a.src[m] + (size_t)(k0 + r) * N + n0 + c4;
  float4 v = *(const float4*)s;
  t[r][c4 + 0] = v.x;
  t[r][c4 + 1] = v.y;
  t[r][c4 + 2] = v.z;
  t[r][c4 + 3] = v.w;
  __syncthreads();
  size_t o = (size_t)(n0 + r) * K + k0 + c4;
  u16* d = a.dst[m];
#pragma unroll
  for (int j = 0; j < 4; j++) d[o + j] = f2bf(t[c4 + j][r]);
}

// ---------------------------------------------------------------- LayerNorm (W=256), batched over branches
struct LN1Args {
  const float* x[3];
  const float* g[3];
  const float* b[3];
  u16* out;  // [3][4096][256]
};
__global__ __launch_bounds__(256) void ln1_kernel(LN1Args a) {
  int lane = threadIdx.x & 63, wid = threadIdx.x >> 6;
  int row = blockIdx.x * 4 + wid;
  int br = blockIdx.y;
  const float* xp = a.x[br] + (size_t)row * 256;
  float v[4], s = 0.f, s2 = 0.f;
#pragma unroll
  for (int j = 0; j < 4; j++) {
    v[j] = xp[lane + 64 * j];
    s += v[j];
    s2 += v[j] * v[j];
  }
#pragma unroll
  for (int m = 32; m; m >>= 1) {
    s += __shfl_xor(s, m);
    s2 += __shfl_xor(s2, m);
  }
  float mean = s * (1.f / 256.f);
  float rstd = rsqrtf(s2 * (1.f / 256.f) - mean * mean + 1e-5f);
  u16* o = a.out + (size_t)br * 1048576 + (size_t)row * 256;
#pragma unroll
  for (int j = 0; j < 4; j++) {
    int c = lane + 64 * j;
    o[c] = f2bf((v[j] - mean) * rstd * a.g[br][c] + a.b[br][c]);
  }
}

// ---------------------------------------------------------------- LayerNorm2 (W=768) -> bf16
__global__ __launch_bounds__(256) void ln2_kernel(const float* xc, const float* g, const float* b,
                                                  u16* oh) {
  int lane = threadIdx.x & 63, wid = threadIdx.x >> 6;
  int row = blockIdx.x * 4 + wid;
  float v[12], s = 0.f, s2 = 0.f;
#pragma unroll
  for (int j = 0; j < 12; j++) {
    int c = lane + 64 * j;
    v[j] = xc[(size_t)(c >> 8) * 1048576 + (size_t)row * 256 + (c & 255)];
    s += v[j];
    s2 += v[j] * v[j];
  }
#pragma unroll
  for (int m = 32; m; m >>= 1) {
    s += __shfl_xor(s, m);
    s2 += __shfl_xor(s2, m);
  }
  float mean = s * (1.f / 768.f);
  float rstd = rsqrtf(s2 * (1.f / 768.f) - mean * mean + 1e-5f);
#pragma unroll
  for (int j = 0; j < 12; j++) {
    int c = lane + 64 * j;
    oh[(size_t)row * 768 + c] = f2bf((v[j] - mean) * rstd * g[c] + b[c]);
  }
}

// ---------------------------------------------------------------- sum NSPLIT KV partials + RMSNorm -> aoN
struct RmsArgs {
  const u16* ao4;
  const float* sc[3];
  u16* aoN;
  int brAo, brAoN;
};
template <int NSPLIT>
__global__ __launch_bounds__(256) void rms_sum_kernel(RmsArgs a) {
  int lane = threadIdx.x & 63, wid = threadIdx.x >> 6;
  int row = blockIdx.x * 4 + wid;
  int br = blockIdx.y;
  const u16* base = a.ao4 + (size_t)br * a.brAo + (size_t)row * 512;
  float v[8], s2 = 0.f;
#pragma unroll
  for (int j = 0; j < 8; j++) {
    int c = lane + 64 * j;
    float acc = 0.f;
#pragma unroll
    for (int s = 0; s < NSPLIT; s++) acc += bf2f(base[(size_t)s * 2097152 + c]);
    v[j] = acc;
    s2 += v[j] * v[j];
  }
#pragma unroll
  for (int m = 32; m; m >>= 1) s2 += __shfl_xor(s2, m);
  float inv = 1.f / (sqrtf(s2) * 0.044194173824159216f + 1e-8f);  // *512^-0.5
  const float* sc = a.sc[br];
  u16* o = a.aoN + (size_t)br * a.brAoN + (size_t)row * 512;
#pragma unroll
  for (int j = 0; j < 8; j++) {
    int c = lane + 64 * j;
    o[c] = f2bf(v[j] * inv * sc[c]);
  }
}

// ---------------------------------------------------------------- QKV GEMM 128x128 (M=4096,N=1536,K=256)
// q,k written natural [bh][n][64] (q scaled 0.125); v written TRANSPOSED [bh][d=64][n=2048].
struct GemmQkvArgs {
  const u16* A;
  const u16* Bt;
  u16 *q, *k, *v;
};
__global__ __launch_bounds__(256) void gemmqkv_kernel(GemmQkvArgs g) {
  __shared__ u16 As[128][40];
  __shared__ u16 Bs[128][40];
  const int tid = threadIdx.x;
  const int lane = tid & 63, wid = tid >> 6;
  const int wm = wid >> 1, wn = wid & 1;
  const int lr = lane & 15, lg = lane >> 4;
  const int m0 = blockIdx.y * 128, n0 = blockIdx.x * 128;
  const int z = blockIdx.z;
  const int K = 256;
  f32x4 acc[4][4] = {};
  const int sr = tid >> 1, sh = (tid & 1) << 4;
  const u16* ga = g.A + (size_t)z * 1048576 + (size_t)(m0 + sr) * K + sh;
  const u16* gb = g.Bt + (size_t)z * 393216 + (size_t)(n0 + sr) * K + sh;
  for (int k0 = 0; k0 < K; k0 += 32) {
    s16x8 a0 = *(const s16x8*)(ga + k0);
    s16x8 a1 = *(const s16x8*)(ga + k0 + 8);
    s16x8 b0 = *(const s16x8*)(gb + k0);
    s16x8 b1 = *(const s16x8*)(gb + k0 + 8);
    __syncthreads();
    *(s16x8*)&As[sr][sh] = a0;
    *(s16x8*)&As[sr][sh + 8] = a1;
    *(s16x8*)&Bs[sr][sh] = b0;
    *(s16x8*)&Bs[sr][sh + 8] = b1;
    __syncthreads();
    s16x8 af[4], bfr[4];
#pragma unroll
    for (int mt = 0; mt < 4; mt++) af[mt] = *(const s16x8*)&As[wm * 64 + mt * 16 + lr][lg * 8];
#pragma unroll
    for (int nt = 0; nt < 4; nt++) bfr[nt] = *(const s16x8*)&Bs[wn * 64 + nt * 16 + lr][lg * 8];
#pragma unroll
    for (int mt = 0; mt < 4; mt++)
#pragma unroll
      for (int nt = 0; nt < 4; nt++) acc[mt][nt] = MFMA(af[mt], bfr[nt], acc[mt][nt]);
  }
  const int seg = n0 >> 9;
  if (seg == 2) {
    u16* vz = g.v + (size_t)z * 2097152;
#pragma unroll
    for (int mt = 0; mt < 4; mt++) {
      int nbase = m0 + wm * 64 + mt * 16 + lg * 4;
      int b = nbase >> 11, n = nbase & 2047;
#pragma unroll
      for (int nt = 0; nt < 4; nt++) {
        int col = n0 + wn * 64 + nt * 16 + lr;
        int hh = (col >> 6) & 7, d = col & 63;
        u16x4 w;
#pragma unroll
        for (int r = 0; r < 4; r++) w[r] = f2bf(acc[mt][nt][r]);
        *(u16x4*)(vz + (size_t)((b << 3) + hh) * 131072 + (size_t)d * 2048 + n) = w;
      }
    }
  } else {
    u16* dst = (seg == 0 ? g.q : g.k) + (size_t)z * 2097152;
    const float scv = (seg == 0) ? 0.125f : 1.0f;
#pragma unroll
    for (int mt = 0; mt < 4; mt++)
#pragma unroll
      for (int nt = 0; nt < 4; nt++)
#pragma unroll
        for (int r = 0; r < 4; r++) {
          int row = m0 + wm * 64 + mt * 16 + lg * 4 + r;
          int col = n0 + wn * 64 + nt * 16 + lr;
          int hh = (col >> 6) & 7, d = col & 63;
          int b = row >> 11, n = row & 2047;
          dst[(size_t)((b << 3) + hh) * 131072 + (size_t)n * 64 + d] = f2bf(acc[mt][nt][r] * scv);
        }
  }
}

// ---------------------------------------------------------------- WO GEMM 64x64 tile (+bias+residual->fp32)
struct Gemm64Args {
  const u16* A;   // [4096][512]
  const u16* Bt;  // [256][512]
  const float* bias[3];
  const float* res[3];
  float* outf;
  int aStr, btStr, outStr;
};
__global__ __launch_bounds__(256) void gemm64_kernel(Gemm64Args g) {
  __shared__ u16 As[64][40];
  __shared__ u16 Bs[64][40];
  const int tid = threadIdx.x;
  const int lane = tid & 63, wid = tid >> 6;
  const int wm = wid >> 1, wn = wid & 1;
  const int lr = lane & 15, lg = lane >> 4;
  const int m0 = blockIdx.y * 64, n0 = blockIdx.x * 64;
  const int z = blockIdx.z;
  const int K = 512;
  f32x4 acc[2][2] = {};
  const int sr = tid >> 2, sh8 = (tid & 3) << 3;
  const u16* ga = g.A + (size_t)z * g.aStr + (size_t)(m0 + sr) * K + sh8;
  const u16* gb = g.Bt + (size_t)z * g.btStr + (size_t)(n0 + sr) * K + sh8;
  for (int k0 = 0; k0 < K; k0 += 32) {
    s16x8 a0 = *(const s16x8*)(ga + k0);
    s16x8 b0 = *(const s16x8*)(gb + k0);
    __syncthreads();
    *(s16x8*)&As[sr][sh8] = a0;
    *(s16x8*)&Bs[sr][sh8] = b0;
    __syncthreads();
    s16x8 af[2], bfr[2];
#pragma unroll
    for (int mt = 0; mt < 2; mt++) af[mt] = *(const s16x8*)&As[wm * 32 + mt * 16 + lr][lg * 8];
#pragma unroll
    for (int nt = 0; nt < 2; nt++) bfr[nt] = *(const s16x8*)&Bs[wn * 32 + nt * 16 + lr][lg * 8];
#pragma unroll
    for (int mt = 0; mt < 2; mt++)
#pragma unroll
      for (int nt = 0; nt < 2; nt++) acc[mt][nt] = MFMA(af[mt], bfr[nt], acc[mt][nt]);
  }
  float* of = g.outf + (size_t)z * g.outStr;
#pragma unroll
  for (int mt = 0; mt < 2; mt++)
#pragma unroll
    for (int nt = 0; nt < 2; nt++)
#pragma unroll
      for (int r = 0; r < 4; r++) {
        int row = m0 + wm * 32 + mt * 16 + lg * 4 + r;
        int col = n0 + wn * 32 + nt * 16 + lr;
        float val = acc[mt][nt][r] + g.bias[z][col] + g.res[z][(size_t)row * 256 + col];
        of[(size_t)row * 256 + col] = val;
      }
}

// ---------------------------------------------------------------- MLP GEMM, 128x64 tile, single bf16 term
struct GemmMlpArgs {
  const u16 *A, *Bt;
  int K;
  const float* bias;
  u16* oh;      // EPI 0
  float* outf;  // EPI 1
};
template <int EPI>
__global__ __launch_bounds__(256) void gemmmlp_kernel(GemmMlpArgs g) {
  __shared__ u16 As[128][40], Bs[64][40];
  const int tid = threadIdx.x;
  const int lane = tid & 63, wid = tid >> 6;
  const int wm = wid >> 1, wn = wid & 1;
  const int lr = lane & 15, lg = lane >> 4;
  const int m0 = blockIdx.y * 128, n0 = blockIdx.x * 64;
  const int K = g.K;
  f32x4 acc[4][2] = {};
  const int sra = tid >> 1, sha = (tid & 1) << 4;
  const int srb = tid >> 2, shb = (tid & 3) << 3;
  const u16* ga = g.A + (size_t)(m0 + sra) * K + sha;
  const u16* gb = g.Bt + (size_t)(n0 + srb) * K + shb;
  for (int k0 = 0; k0 < K; k0 += 32) {
    s16x8 a0 = *(const s16x8*)(ga + k0);
    s16x8 a1 = *(const s16x8*)(ga + k0 + 8);
    s16x8 b0 = *(const s16x8*)(gb + k0);
    __syncthreads();
    *(s16x8*)&As[sra][sha] = a0;
    *(s16x8*)&As[sra][sha + 8] = a1;
    *(s16x8*)&Bs[srb][shb] = b0;
    __syncthreads();
    s16x8 af[4], bfr[2];
#pragma unroll
    for (int mt = 0; mt < 4; mt++) af[mt] = *(const s16x8*)&As[wm * 64 + mt * 16 + lr][lg * 8];
#pragma unroll
    for (int nt = 0; nt < 2; nt++) bfr[nt] = *(const s16x8*)&Bs[wn * 32 + nt * 16 + lr][lg * 8];
#pragma unroll
    for (int mt = 0; mt < 4; mt++)
#pragma unroll
      for (int nt = 0; nt < 2; nt++) acc[mt][nt] = MFMA(af[mt], bfr[nt], acc[mt][nt]);
  }
#pragma unroll
  for (int mt = 0; mt < 4; mt++)
#pragma unroll
    for (int nt = 0; nt < 2; nt++)
#pragma unroll
      for (int r = 0; r < 4; r++) {
        int row = m0 + wm * 64 + mt * 16 + lg * 4 + r;
        int col = n0 + wn * 32 + nt * 16 + lr;
        float val = acc[mt][nt][r] + g.bias[col];
        if (EPI == 0) {
          float ge = 0.5f * val * (1.0f + erff(val * 0.70710678118654752f));
          g.oh[(size_t)row * 1024 + col] = f2bf(ge);
        } else {
          int chunk = col >> 8, cc = col & 255;
          float* p = g.outf + (size_t)chunk * 1048576 + (size_t)row * 256 + cc;
          *p = val + *p;
        }
      }
}

// ---------------------------------------------------------------- ReLU attention v5: in-register P
// S^T = mfma32(A=K rows, B=Q rows) -> lane holds P[q=l31][16 kv per nt-tile] (C layout m74/m101).
// PV  = mfma32(A=pa from own st values, B=V' rows) with k-slot permutation
// kv_v(k) = (k&3)+8*((k>>2)&1)+4*(k>>3) compensated by b64 V reads from natural Vt[d][kv].
// No Ps LDS, no tr-read, no permlane. XCD-swizzled 1-D grid as before.
template <int NSPLIT, int NBR>
__global__ __launch_bounds__(256) void attn_kernel(const u16* q, const u16* k, const u16* vT,
                                                   u16* ao4, int brQkv, int brAo) {
  __shared__ u16 Ks[64][72];  // [kv][d]
  __shared__ u16 Vt[64][72];  // [d][kv]
  const int tid = threadIdx.x;
  const int lane = tid & 63, wid = tid >> 6;
  const int l31 = lane & 31, hi = lane >> 5;
  const int NG = NBR * 16 * NSPLIT;
  const int L = blockIdx.x;
  const int qb = L / NG, g = L % NG;
  const int br = g / (16 * NSPLIT);
  const int rest = g % (16 * NSPLIT);
  const int bh = rest / NSPLIT, sp = rest % NSPLIT;
  const size_t boff = (size_t)br * brQkv + (size_t)bh * 131072;
  const u16* qp = q + boff;
  const u16* kp = k + boff;
  const u16* vp = vT + boff;
  // Q B-frags: chunk c covers d = c*16 + hi*8 + i (natural row reads)
  s16x8 qf[4];
  {
    const u16* qrow = qp + (size_t)(qb * 128 + wid * 32 + l31) * 64 + hi * 8;
#pragma unroll
    for (int c = 0; c < 4; c++) qf[c] = *(const s16x8*)(qrow + c * 16);
  }
  f32x16 oacc[2];
#pragma unroll
  for (int dt = 0; dt < 2; dt++)
#pragma unroll
    for (int i = 0; i < 16; i++) oacc[dt][i] = 0.f;

  const int sr = tid >> 2, sc = (tid & 3) << 4;
  const u16* kg = kp + sr * 64 + sc;    // K rows [kv][d]
  const u16* vg = vp + sr * 2048 + sc;  // vT rows [d][n]
  const int TPS = 32 / NSPLIT;
  const int ktL = sp * TPS, ktH = ktL + TPS;
  s16x8 kv0 = *(const s16x8*)(kg + ktL * 4096);
  s16x8 kv1 = *(const s16x8*)(kg + ktL * 4096 + 8);
  s16x8 vv0 = *(const s16x8*)(vg + ktL * 64);
  s16x8 vv1 = *(const s16x8*)(vg + ktL * 64 + 8);
  for (int kt = ktL; kt < ktH; kt++) {
    __syncthreads();  // prev iter's Ks/Vt reads done
    *(s16x8*)&Ks[sr][sc] = kv0;
    *(s16x8*)&Ks[sr][sc + 8] = kv1;
    *(s16x8*)&Vt[sr][sc] = vv0;
    *(s16x8*)&Vt[sr][sc + 8] = vv1;
    __syncthreads();
    const int nx = (kt + 1 < ktH) ? kt + 1 : kt;
    kv0 = *(const s16x8*)(kg + nx * 4096);
    kv1 = *(const s16x8*)(kg + nx * 4096 + 8);
    vv0 = *(const s16x8*)(vg + nx * 64);
    vv1 = *(const s16x8*)(vg + nx * 64 + 8);
#pragma unroll
    for (int nt = 0; nt < 2; nt++) {
      // S^T[kv][q] over this 32-kv tile: A = K rows, B = Q rows, 4 chained k(d)-chunks
      f32x16 st;
#pragma unroll
      for (int i = 0; i < 16; i++) st[i] = 0.f;
#pragma unroll
      for (int c = 0; c < 4; c++) {
        s16x8 kf = *(const s16x8*)&Ks[nt * 32 + l31][c * 16 + hi * 8];
        st = MFMA32(kf, qf[c], st);
      }
      // pa0 = relu(st[0..7]), pa1 = relu(st[8..15]) packed bf16 (slot i -> kv_v(hi*8+i))
      unsigned u[8];
#pragma unroll
      for (int j = 0; j < 8; j++) {
        float p0 = fmaxf(st[2 * j], 0.f);
        float p1 = fmaxf(st[2 * j + 1], 0.f);
        asm("v_cvt_pk_bf16_f32 %0, %1, %2" : "=v"(u[j]) : "v"(p0), "v"(p1));
      }
      union { unsigned w[4]; s16x8 s; } PA0, PA1;
#pragma unroll
      for (int j = 0; j < 4; j++) {
        PA0.w[j] = u[j];
        PA1.w[j] = u[j + 4];
      }
      // PV: B-frag slot i needs V[kv_v(hi*8+i)][d] = Vt[d][base + runs {4hi..}, {8+4hi..}]
#pragma unroll
      for (int c2 = 0; c2 < 2; c2++) {
        const int base = nt * 32 + c2 * 16;
#pragma unroll
        for (int dt = 0; dt < 2; dt++) {
          const u16* vrow = &Vt[dt * 32 + l31][0];
          union { u16x4 h[2]; s16x8 s; } VF;
          VF.h[0] = *(const u16x4*)(vrow + base + 4 * hi);
          VF.h[1] = *(const u16x4*)(vrow + base + 8 + 4 * hi);
          oacc[dt] = MFMA32(c2 == 0 ? PA0.s : PA1.s, VF.s, oacc[dt]);
        }
      }
    }
  }
  u16* aop = ao4 + (size_t)br * brAo + (size_t)sp * 2097152;
  const int b = bh >> 3, h = bh & 7;
#pragma unroll
  for (int dt = 0; dt < 2; dt++)
#pragma unroll
    for (int r = 0; r < 16; r++) {
      int qrow = qb * 128 + wid * 32 + (r & 3) + 8 * (r >> 2) + 4 * hi;
      aop[(size_t)(b * 2048 + qrow) * 512 + h * 64 + dt * 32 + l31] = f2bf(oacc[dt][r]);
    }
}

// ----------------------------------------------------------------
extern "C" void kernel_launch(void* const* d_in, const int* in_sizes, int n_in,
                              void* d_out, int out_size, void* d_ws, size_t ws_size,
                              hipStream_t stream) {
  const float* X[3] = {(const float*)d_in[0], (const float*)d_in[1], (const float*)d_in[2]};
  const float* G1[3] = {(const float*)d_in[3], (const float*)d_in[9], (const float*)d_in[15]};
  const float* B1[3] = {(const float*)d_in[4], (const float*)d_in[10], (const float*)d_in[16]};
  const float* WQKV[3] = {(const float*)d_in[5], (const float*)d_in[11], (const float*)d_in[17]};
  const float* RMS[3] = {(const float*)d_in[6], (const float*)d_in[12], (const float*)d_in[18]};
  const float* WO[3] = {(const float*)d_in[7], (const float*)d_in[13], (const float*)d_in[19]};
  const float* BO[3] = {(const float*)d_in[8], (const float*)d_in[14], (const float*)d_in[20]};
  const float* G2 = (const float*)d_in[21];
  const float* B2 = (const float*)d_in[22];
  const float* WFC1 = (const float*)d_in[23];
  const float* BFC1 = (const float*)d_in[24];
  const float* WFC2 = (const float*)d_in[25];
  const float* BFC2 = (const float*)d_in[26];
  float* dout = (float*)d_out;
  u16* W = (u16*)d_ws;

  const bool batched = ws_size >= 88080384ULL;  // 44,040,192 u16 elems

  // 1) all weight transposes, one launch (shared)
  u16* wqkvT = W;            // [3][1536][256]
  u16* woT = W + 1179648;    // [3][256][512]
  u16* fc1T = W + 1572864;   // [1024][768]
  u16* fc2T = W + 2359296;   // [768][1024]
  u16* xn = W + 3145728;     // [3][4096][256]   .. 6,291,456
  TrArgs ta;
  const float* srcs[8] = {WQKV[0], WQKV[1], WQKV[2], WO[0], WO[1], WO[2], WFC1, WFC2};
  u16* dsts[8] = {wqkvT, wqkvT + 393216, wqkvT + 786432, woT, woT + 131072, woT + 262144, fc1T, fc2T};
  int Ks_[8] = {256, 256, 256, 512, 512, 512, 768, 1024};
  int Ns_[8] = {1536, 1536, 1536, 256, 256, 256, 1024, 768};
  int tst[9] = {0, 384, 768, 1152, 1280, 1408, 1536, 2304, 3072};
  for (int i = 0; i < 8; i++) {
    ta.src[i] = srcs[i];
    ta.dst[i] = dsts[i];
    ta.K[i] = Ks_[i];
    ta.N[i] = Ns_[i];
    ta.tstart[i] = tst[i];
  }
  ta.tstart[8] = tst[8];
  hipLaunchKernelGGL(tr_kernel, dim3(3072), dim3(256), 0, stream, ta);

  // 2) LN1 (shared)
  LN1Args la;
  for (int i = 0; i < 3; i++) {
    la.x[i] = X[i];
    la.g[i] = G1[i];
    la.b[i] = B1[i];
  }
  la.out = xn;
  hipLaunchKernelGGL(ln1_kernel, dim3(1024, 3), dim3(256), 0, stream, la);

  u16 *ln2b, *hbuf;

  if (batched) {
    u16* qall = W + 6291456;
    u16* kall = W + 12582912;
    u16* vall = W + 18874368;
    u16* ao4 = W + 25165824;   // [3][2][4096][512]
    u16* aoN = W + 37748736;   // [3][4096][512]
    ln2b = W + 6291456;
    hbuf = W + 9437184;

    GemmQkvArgs gq = {xn, wqkvT, qall, kall, vall};
    hipLaunchKernelGGL(gemmqkv_kernel, dim3(12, 32, 3), dim3(256), 0, stream, gq);

    hipLaunchKernelGGL((attn_kernel<2, 3>), dim3(1536), dim3(256), 0, stream,
                       qall, kall, vall, ao4, 2097152, 4194304);

    RmsArgs ra;
    ra.ao4 = ao4;
    for (int i = 0; i < 3; i++) ra.sc[i] = RMS[i];
    ra.aoN = aoN;
    ra.brAo = 4194304;
    ra.brAoN = 2097152;
    hipLaunchKernelGGL(rms_sum_kernel<2>, dim3(1024, 3), dim3(256), 0, stream, ra);

    Gemm64Args gw;
    gw.A = aoN;
    gw.Bt = woT;
    for (int i = 0; i < 3; i++) {
      gw.bias[i] = BO[i];
      gw.res[i] = X[i];
    }
    gw.outf = dout;
    gw.aStr = 2097152;
    gw.btStr = 131072;
    gw.outStr = 1048576;
    hipLaunchKernelGGL(gemm64_kernel, dim3(4, 64, 3), dim3(256), 0, stream, gw);
  } else {
    // Serial fallback (peak 44 MiB)
    u16* qz = W + 6291456;
    u16* kz = W + 8388608;
    u16* vz = W + 10485760;
    u16* ao4 = W + 12582912;  // [4][4096][512]
    u16* aoN = W + 20971520;
    ln2b = W + 6291456;
    hbuf = W + 9437184;

    for (int z = 0; z < 3; z++) {
      GemmQkvArgs gq = {xn + (size_t)z * 1048576, wqkvT + (size_t)z * 393216, qz, kz, vz};
      hipLaunchKernelGGL(gemmqkv_kernel, dim3(12, 32, 1), dim3(256), 0, stream, gq);

      hipLaunchKernelGGL((attn_kernel<4, 1>), dim3(1024), dim3(256), 0, stream,
                         qz, kz, vz, ao4, 0, 0);

      RmsArgs ra;
      ra.ao4 = ao4;
      ra.sc[0] = RMS[z];
      ra.sc[1] = RMS[z];
      ra.sc[2] = RMS[z];
      ra.aoN = aoN;
      ra.brAo = 0;
      ra.brAoN = 0;
      hipLaunchKernelGGL(rms_sum_kernel<4>, dim3(1024, 1), dim3(256), 0, stream, ra);

      Gemm64Args gw;
      gw.A = aoN;
      gw.Bt = woT + (size_t)z * 131072;
      for (int i = 0; i < 3; i++) {
        gw.bias[i] = BO[z];
        gw.res[i] = X[z];
      }
      gw.outf = dout + (size_t)z * 1048576;
      gw.aStr = 0;
      gw.btStr = 0;
      gw.outStr = 0;
      hipLaunchKernelGGL(gemm64_kernel, dim3(4, 64, 1), dim3(256), 0, stream, gw);
    }
  }

  // 4) LN2 -> bf16
  hipLaunchKernelGGL(ln2_kernel, dim3(1024), dim3(256), 0, stream, dout, G2, B2, ln2b);

  // 5) FC1 (M=4096,N=1024,K=768) + gelu -> hbuf
  GemmMlpArgs g1 = {};
  g1.A = ln2b;
  g1.Bt = fc1T;
  g1.K = 768;
  g1.bias = BFC1;
  g1.oh = hbuf;
  hipLaunchKernelGGL(gemmmlp_kernel<0>, dim3(16, 32), dim3(256), 0, stream, g1);

  // 6) FC2 (M=4096,N=768,K=1024) + bias + residual RMW on d_out
  GemmMlpArgs g2 = {};
  g2.A = hbuf;
  g2.Bt = fc2T;
  g2.K = 1024;
  g2.bias = BFC2;
  g2.outf = dout;
  hipLaunchKernelGGL(gemmmlp_kernel<1>, dim3(12, 32), dim3(256), 0, stream, g2);
}

// Round 12
// 166.373 us; speedup vs baseline: 1.1339x; 1.0843x over previous
//
#include <hip/hip_runtime.h>

using u16 = unsigned short;
typedef __attribute__((ext_vector_type(4))) float f32x4;
typedef __attribute__((ext_vector_type(16))) float f32x16;
typedef __attribute__((ext_vector_type(8))) short s16x8;
typedef __attribute__((ext_vector_type(4))) unsigned short u16x4;

#define MFMA(a, b, c) __builtin_amdgcn_mfma_f32_16x16x32_bf16((a), (b), (c), 0, 0, 0)
#define MFMA32(a, b, c) __builtin_amdgcn_mfma_f32_32x32x16_bf16((a), (b), (c), 0, 0, 0)

__device__ __forceinline__ u16 f2bf(float f) {
  unsigned u = __float_as_uint(f);
  u += 0x7fff + ((u >> 16) & 1);
  return (u16)(u >> 16);
}
__device__ __forceinline__ float bf2f(u16 h) {
  return __uint_as_float((unsigned)h << 16);
}

// XOR swizzle for [64][72] u16 LDS tiles: spreads rows-8-apart bank aliases.
// Bijective within each 64B line (array size 9216 = 144*64). Same formula on write+read.
__device__ __forceinline__ u16* swz(u16* base, int r, int cu16) {
  unsigned off = ((unsigned)(r * 72 + cu16) * 2u) ^ ((((unsigned)r >> 3) & 3u) << 4);
  return (u16*)((char*)base + off);
}

// ---------------------------------------------------------------- transpose+convert all weights, one launch
struct TrArgs {
  const float* src[8];
  u16* dst[8];
  int K[8], N[8];
  int tstart[9];
};
__global__ __launch_bounds__(256) void tr_kernel(TrArgs a) {
  __shared__ float t[32][33];
  int tile = blockIdx.x;
  int m = 0;
  while (tile >= a.tstart[m + 1]) m++;
  int ti = tile - a.tstart[m];
  int K = a.K[m], N = a.N[m];
  int ntn = N >> 5;
  int tk = ti / ntn;
  int k0 = tk << 5, n0 = (ti - tk * ntn) << 5;
  int r = threadIdx.x >> 3, c4 = (threadIdx.x & 7) << 2;
  const float* s = a.src[m] + (size_t)(k0 + r) * N + n0 + c4;
  float4 v = *(const float4*)s;
  t[r][c4 + 0] = v.x;
  t[r][c4 + 1] = v.y;
  t[r][c4 + 2] = v.z;
  t[r][c4 + 3] = v.w;
  __syncthreads();
  size_t o = (size_t)(n0 + r) * K + k0 + c4;
  u16* d = a.dst[m];
#pragma unroll
  for (int j = 0; j < 4; j++) d[o + j] = f2bf(t[c4 + j][r]);
}

// ---------------------------------------------------------------- LayerNorm (W=256), batched over branches
struct LN1Args {
  const float* x[3];
  const float* g[3];
  const float* b[3];
  u16* out;  // [3][4096][256]
};
__global__ __launch_bounds__(256) void ln1_kernel(LN1Args a) {
  int lane = threadIdx.x & 63, wid = threadIdx.x >> 6;
  int row = blockIdx.x * 4 + wid;
  int br = blockIdx.y;
  const float* xp = a.x[br] + (size_t)row * 256;
  float v[4], s = 0.f, s2 = 0.f;
#pragma unroll
  for (int j = 0; j < 4; j++) {
    v[j] = xp[lane + 64 * j];
    s += v[j];
    s2 += v[j] * v[j];
  }
#pragma unroll
  for (int m = 32; m; m >>= 1) {
    s += __shfl_xor(s, m);
    s2 += __shfl_xor(s2, m);
  }
  float mean = s * (1.f / 256.f);
  float rstd = rsqrtf(s2 * (1.f / 256.f) - mean * mean + 1e-5f);
  u16* o = a.out + (size_t)br * 1048576 + (size_t)row * 256;
#pragma unroll
  for (int j = 0; j < 4; j++) {
    int c = lane + 64 * j;
    o[c] = f2bf((v[j] - mean) * rstd * a.g[br][c] + a.b[br][c]);
  }
}

// ---------------------------------------------------------------- LayerNorm2 (W=768) -> bf16
__global__ __launch_bounds__(256) void ln2_kernel(const float* xc, const float* g, const float* b,
                                                  u16* oh) {
  int lane = threadIdx.x & 63, wid = threadIdx.x >> 6;
  int row = blockIdx.x * 4 + wid;
  float v[12], s = 0.f, s2 = 0.f;
#pragma unroll
  for (int j = 0; j < 12; j++) {
    int c = lane + 64 * j;
    v[j] = xc[(size_t)(c >> 8) * 1048576 + (size_t)row * 256 + (c & 255)];
    s += v[j];
    s2 += v[j] * v[j];
  }
#pragma unroll
  for (int m = 32; m; m >>= 1) {
    s += __shfl_xor(s, m);
    s2 += __shfl_xor(s2, m);
  }
  float mean = s * (1.f / 768.f);
  float rstd = rsqrtf(s2 * (1.f / 768.f) - mean * mean + 1e-5f);
#pragma unroll
  for (int j = 0; j < 12; j++) {
    int c = lane + 64 * j;
    oh[(size_t)row * 768 + c] = f2bf((v[j] - mean) * rstd * g[c] + b[c]);
  }
}

// ---------------------------------------------------------------- sum NSPLIT KV partials + RMSNorm -> aoN
struct RmsArgs {
  const u16* ao4;
  const float* sc[3];
  u16* aoN;
  int brAo, brAoN;
};
template <int NSPLIT>
__global__ __launch_bounds__(256) void rms_sum_kernel(RmsArgs a) {
  int lane = threadIdx.x & 63, wid = threadIdx.x >> 6;
  int row = blockIdx.x * 4 + wid;
  int br = blockIdx.y;
  const u16* base = a.ao4 + (size_t)br * a.brAo + (size_t)row * 512;
  float v[8], s2 = 0.f;
#pragma unroll
  for (int j = 0; j < 8; j++) {
    int c = lane + 64 * j;
    float acc = 0.f;
#pragma unroll
    for (int s = 0; s < NSPLIT; s++) acc += bf2f(base[(size_t)s * 2097152 + c]);
    v[j] = acc;
    s2 += v[j] * v[j];
  }
#pragma unroll
  for (int m = 32; m; m >>= 1) s2 += __shfl_xor(s2, m);
  float inv = 1.f / (sqrtf(s2) * 0.044194173824159216f + 1e-8f);  // *512^-0.5
  const float* sc = a.sc[br];
  u16* o = a.aoN + (size_t)br * a.brAoN + (size_t)row * 512;
#pragma unroll
  for (int j = 0; j < 8; j++) {
    int c = lane + 64 * j;
    o[c] = f2bf(v[j] * inv * sc[c]);
  }
}

// ---------------------------------------------------------------- QKV GEMM 128x128 (M=4096,N=1536,K=256)
// q,k written natural [bh][n][64] (q scaled 0.125); v written TRANSPOSED [bh][d=64][n=2048].
struct GemmQkvArgs {
  const u16* A;
  const u16* Bt;
  u16 *q, *k, *v;
};
__global__ __launch_bounds__(256) void gemmqkv_kernel(GemmQkvArgs g) {
  __shared__ u16 As[128][40];
  __shared__ u16 Bs[128][40];
  const int tid = threadIdx.x;
  const int lane = tid & 63, wid = tid >> 6;
  const int wm = wid >> 1, wn = wid & 1;
  const int lr = lane & 15, lg = lane >> 4;
  const int m0 = blockIdx.y * 128, n0 = blockIdx.x * 128;
  const int z = blockIdx.z;
  const int K = 256;
  f32x4 acc[4][4] = {};
  const int sr = tid >> 1, sh = (tid & 1) << 4;
  const u16* ga = g.A + (size_t)z * 1048576 + (size_t)(m0 + sr) * K + sh;
  const u16* gb = g.Bt + (size_t)z * 393216 + (size_t)(n0 + sr) * K + sh;
  for (int k0 = 0; k0 < K; k0 += 32) {
    s16x8 a0 = *(const s16x8*)(ga + k0);
    s16x8 a1 = *(const s16x8*)(ga + k0 + 8);
    s16x8 b0 = *(const s16x8*)(gb + k0);
    s16x8 b1 = *(const s16x8*)(gb + k0 + 8);
    __syncthreads();
    *(s16x8*)&As[sr][sh] = a0;
    *(s16x8*)&As[sr][sh + 8] = a1;
    *(s16x8*)&Bs[sr][sh] = b0;
    *(s16x8*)&Bs[sr][sh + 8] = b1;
    __syncthreads();
    s16x8 af[4], bfr[4];
#pragma unroll
    for (int mt = 0; mt < 4; mt++) af[mt] = *(const s16x8*)&As[wm * 64 + mt * 16 + lr][lg * 8];
#pragma unroll
    for (int nt = 0; nt < 4; nt++) bfr[nt] = *(const s16x8*)&Bs[wn * 64 + nt * 16 + lr][lg * 8];
#pragma unroll
    for (int mt = 0; mt < 4; mt++)
#pragma unroll
      for (int nt = 0; nt < 4; nt++) acc[mt][nt] = MFMA(af[mt], bfr[nt], acc[mt][nt]);
  }
  const int seg = n0 >> 9;
  if (seg == 2) {
    u16* vz = g.v + (size_t)z * 2097152;
#pragma unroll
    for (int mt = 0; mt < 4; mt++) {
      int nbase = m0 + wm * 64 + mt * 16 + lg * 4;
      int b = nbase >> 11, n = nbase & 2047;
#pragma unroll
      for (int nt = 0; nt < 4; nt++) {
        int col = n0 + wn * 64 + nt * 16 + lr;
        int hh = (col >> 6) & 7, d = col & 63;
        u16x4 w;
#pragma unroll
        for (int r = 0; r < 4; r++) w[r] = f2bf(acc[mt][nt][r]);
        *(u16x4*)(vz + (size_t)((b << 3) + hh) * 131072 + (size_t)d * 2048 + n) = w;
      }
    }
  } else {
    u16* dst = (seg == 0 ? g.q : g.k) + (size_t)z * 2097152;
    const float scv = (seg == 0) ? 0.125f : 1.0f;
#pragma unroll
    for (int mt = 0; mt < 4; mt++)
#pragma unroll
      for (int nt = 0; nt < 4; nt++)
#pragma unroll
        for (int r = 0; r < 4; r++) {
          int row = m0 + wm * 64 + mt * 16 + lg * 4 + r;
          int col = n0 + wn * 64 + nt * 16 + lr;
          int hh = (col >> 6) & 7, d = col & 63;
          int b = row >> 11, n = row & 2047;
          dst[(size_t)((b << 3) + hh) * 131072 + (size_t)n * 64 + d] = f2bf(acc[mt][nt][r] * scv);
        }
  }
}

// ---------------------------------------------------------------- WO GEMM 64x64 tile (+bias+residual->fp32)
struct Gemm64Args {
  const u16* A;   // [4096][512]
  const u16* Bt;  // [256][512]
  const float* bias[3];
  const float* res[3];
  float* outf;
  int aStr, btStr, outStr;
};
__global__ __launch_bounds__(256) void gemm64_kernel(Gemm64Args g) {
  __shared__ u16 As[64][40];
  __shared__ u16 Bs[64][40];
  const int tid = threadIdx.x;
  const int lane = tid & 63, wid = tid >> 6;
  const int wm = wid >> 1, wn = wid & 1;
  const int lr = lane & 15, lg = lane >> 4;
  const int m0 = blockIdx.y * 64, n0 = blockIdx.x * 64;
  const int z = blockIdx.z;
  const int K = 512;
  f32x4 acc[2][2] = {};
  const int sr = tid >> 2, sh8 = (tid & 3) << 3;
  const u16* ga = g.A + (size_t)z * g.aStr + (size_t)(m0 + sr) * K + sh8;
  const u16* gb = g.Bt + (size_t)z * g.btStr + (size_t)(n0 + sr) * K + sh8;
  for (int k0 = 0; k0 < K; k0 += 32) {
    s16x8 a0 = *(const s16x8*)(ga + k0);
    s16x8 b0 = *(const s16x8*)(gb + k0);
    __syncthreads();
    *(s16x8*)&As[sr][sh8] = a0;
    *(s16x8*)&Bs[sr][sh8] = b0;
    __syncthreads();
    s16x8 af[2], bfr[2];
#pragma unroll
    for (int mt = 0; mt < 2; mt++) af[mt] = *(const s16x8*)&As[wm * 32 + mt * 16 + lr][lg * 8];
#pragma unroll
    for (int nt = 0; nt < 2; nt++) bfr[nt] = *(const s16x8*)&Bs[wn * 32 + nt * 16 + lr][lg * 8];
#pragma unroll
    for (int mt = 0; mt < 2; mt++)
#pragma unroll
      for (int nt = 0; nt < 2; nt++) acc[mt][nt] = MFMA(af[mt], bfr[nt], acc[mt][nt]);
  }
  float* of = g.outf + (size_t)z * g.outStr;
#pragma unroll
  for (int mt = 0; mt < 2; mt++)
#pragma unroll
    for (int nt = 0; nt < 2; nt++)
#pragma unroll
      for (int r = 0; r < 4; r++) {
        int row = m0 + wm * 32 + mt * 16 + lg * 4 + r;
        int col = n0 + wn * 32 + nt * 16 + lr;
        float val = acc[mt][nt][r] + g.bias[z][col] + g.res[z][(size_t)row * 256 + col];
        of[(size_t)row * 256 + col] = val;
      }
}

// ---------------------------------------------------------------- MLP GEMM, 128x64 tile, single bf16 term
struct GemmMlpArgs {
  const u16 *A, *Bt;
  int K;
  const float* bias;
  u16* oh;      // EPI 0
  float* outf;  // EPI 1
};
template <int EPI>
__global__ __launch_bounds__(256) void gemmmlp_kernel(GemmMlpArgs g) {
  __shared__ u16 As[128][40], Bs[64][40];
  const int tid = threadIdx.x;
  const int lane = tid & 63, wid = tid >> 6;
  const int wm = wid >> 1, wn = wid & 1;
  const int lr = lane & 15, lg = lane >> 4;
  const int m0 = blockIdx.y * 128, n0 = blockIdx.x * 64;
  const int K = g.K;
  f32x4 acc[4][2] = {};
  const int sra = tid >> 1, sha = (tid & 1) << 4;
  const int srb = tid >> 2, shb = (tid & 3) << 3;
  const u16* ga = g.A + (size_t)(m0 + sra) * K + sha;
  const u16* gb = g.Bt + (size_t)(n0 + srb) * K + shb;
  for (int k0 = 0; k0 < K; k0 += 32) {
    s16x8 a0 = *(const s16x8*)(ga + k0);
    s16x8 a1 = *(const s16x8*)(ga + k0 + 8);
    s16x8 b0 = *(const s16x8*)(gb + k0);
    __syncthreads();
    *(s16x8*)&As[sra][sha] = a0;
    *(s16x8*)&As[sra][sha + 8] = a1;
    *(s16x8*)&Bs[srb][shb] = b0;
    __syncthreads();
    s16x8 af[4], bfr[2];
#pragma unroll
    for (int mt = 0; mt < 4; mt++) af[mt] = *(const s16x8*)&As[wm * 64 + mt * 16 + lr][lg * 8];
#pragma unroll
    for (int nt = 0; nt < 2; nt++) bfr[nt] = *(const s16x8*)&Bs[wn * 32 + nt * 16 + lr][lg * 8];
#pragma unroll
    for (int mt = 0; mt < 4; mt++)
#pragma unroll
      for (int nt = 0; nt < 2; nt++) acc[mt][nt] = MFMA(af[mt], bfr[nt], acc[mt][nt]);
  }
#pragma unroll
  for (int mt = 0; mt < 4; mt++)
#pragma unroll
    for (int nt = 0; nt < 2; nt++)
#pragma unroll
      for (int r = 0; r < 4; r++) {
        int row = m0 + wm * 64 + mt * 16 + lg * 4 + r;
        int col = n0 + wn * 32 + nt * 16 + lr;
        float val = acc[mt][nt][r] + g.bias[col];
        if (EPI == 0) {
          float ge = 0.5f * val * (1.0f + erff(val * 0.70710678118654752f));
          g.oh[(size_t)row * 1024 + col] = f2bf(ge);
        } else {
          int chunk = col >> 8, cc = col & 255;
          float* p = g.outf + (size_t)chunk * 1048576 + (size_t)row * 256 + cc;
          *p = val + *p;
        }
      }
}

// ---------------------------------------------------------------- ReLU attention v6: in-register P, QBLK=256
// 64 q/wave (2 q-halves share every Ks/Vt fragment read), XOR-swizzled LDS, XCD-grouped 1-D grid.
template <int NSPLIT, int NBR>
__global__ __launch_bounds__(256, 3) void attn_kernel(const u16* q, const u16* k, const u16* vT,
                                                      u16* ao4, int brQkv, int brAo) {
  __shared__ u16 Ks[64][72];  // [kv][d], swizzled
  __shared__ u16 Vt[64][72];  // [d][kv], swizzled
  const int tid = threadIdx.x;
  const int lane = tid & 63, wid = tid >> 6;
  const int l31 = lane & 31, hi = lane >> 5;
  const int NG = NBR * 16 * NSPLIT;
  const int L = blockIdx.x;
  const int qb = L / NG, g = L % NG;
  const int br = g / (16 * NSPLIT);
  const int rest = g % (16 * NSPLIT);
  const int bh = rest / NSPLIT, sp = rest % NSPLIT;
  const size_t boff = (size_t)br * brQkv + (size_t)bh * 131072;
  const u16* qp = q + boff;
  const u16* kp = k + boff;
  const u16* vp = vT + boff;
  // Q B-frags for both q-halves: chunk c covers d = c*16 + hi*8 + i
  s16x8 qf[2][4];
#pragma unroll
  for (int qh = 0; qh < 2; qh++) {
    const u16* qrow = qp + (size_t)(qb * 256 + wid * 64 + qh * 32 + l31) * 64 + hi * 8;
#pragma unroll
    for (int c = 0; c < 4; c++) qf[qh][c] = *(const s16x8*)(qrow + c * 16);
  }
  f32x16 oacc[2][2];  // [qh][dt]
#pragma unroll
  for (int qh = 0; qh < 2; qh++)
#pragma unroll
    for (int dt = 0; dt < 2; dt++)
#pragma unroll
      for (int i = 0; i < 16; i++) oacc[qh][dt][i] = 0.f;

  const int sr = tid >> 2, sc = (tid & 3) << 4;
  const u16* kg = kp + sr * 64 + sc;    // K rows [kv][d]
  const u16* vg = vp + sr * 2048 + sc;  // vT rows [d][n]
  const int TPS = 32 / NSPLIT;
  const int ktL = sp * TPS, ktH = ktL + TPS;
  s16x8 kv0 = *(const s16x8*)(kg + ktL * 4096);
  s16x8 kv1 = *(const s16x8*)(kg + ktL * 4096 + 8);
  s16x8 vv0 = *(const s16x8*)(vg + ktL * 64);
  s16x8 vv1 = *(const s16x8*)(vg + ktL * 64 + 8);
  u16* Ks0 = &Ks[0][0];
  u16* Vt0 = &Vt[0][0];
  for (int kt = ktL; kt < ktH; kt++) {
    __syncthreads();  // prev iter's Ks/Vt reads done
    *(s16x8*)swz(Ks0, sr, sc) = kv0;
    *(s16x8*)swz(Ks0, sr, sc + 8) = kv1;
    *(s16x8*)swz(Vt0, sr, sc) = vv0;
    *(s16x8*)swz(Vt0, sr, sc + 8) = vv1;
    __syncthreads();
    const int nx = (kt + 1 < ktH) ? kt + 1 : kt;
    kv0 = *(const s16x8*)(kg + nx * 4096);
    kv1 = *(const s16x8*)(kg + nx * 4096 + 8);
    vv0 = *(const s16x8*)(vg + nx * 64);
    vv1 = *(const s16x8*)(vg + nx * 64 + 8);
#pragma unroll
    for (int nt = 0; nt < 2; nt++) {
      // S^T[kv][q] for both q-halves; kf shared
      f32x16 st0, st1;
#pragma unroll
      for (int i = 0; i < 16; i++) {
        st0[i] = 0.f;
        st1[i] = 0.f;
      }
#pragma unroll
      for (int c = 0; c < 4; c++) {
        s16x8 kf = *(const s16x8*)swz(Ks0, nt * 32 + l31, c * 16 + hi * 8);
        st0 = MFMA32(kf, qf[0][c], st0);
        st1 = MFMA32(kf, qf[1][c], st1);
      }
      // pack relu(P) -> bf16 A-frags (slot i -> kv_v(hi*8+i) = (i&3)+8*((i>>2)&1)+4*hi... per-pair order)
      union { unsigned w[4]; s16x8 s; } PA[2][2];
#pragma unroll
      for (int qh = 0; qh < 2; qh++) {
        const f32x16& st = qh ? st1 : st0;
#pragma unroll
        for (int j = 0; j < 8; j++) {
          float p0 = fmaxf(st[2 * j], 0.f);
          float p1 = fmaxf(st[2 * j + 1], 0.f);
          unsigned w;
          asm("v_cvt_pk_bf16_f32 %0, %1, %2" : "=v"(w) : "v"(p0), "v"(p1));
          PA[qh][j >> 2].w[j & 3] = w;
        }
      }
      // PV: V B-frags shared by both q-halves
#pragma unroll
      for (int c2 = 0; c2 < 2; c2++) {
        const int base = nt * 32 + c2 * 16;
#pragma unroll
        for (int dt = 0; dt < 2; dt++) {
          union { u16x4 h[2]; s16x8 s; } VF;
          VF.h[0] = *(const u16x4*)swz(Vt0, dt * 32 + l31, base + 4 * hi);
          VF.h[1] = *(const u16x4*)swz(Vt0, dt * 32 + l31, base + 8 + 4 * hi);
          oacc[0][dt] = MFMA32(PA[0][c2].s, VF.s, oacc[0][dt]);
          oacc[1][dt] = MFMA32(PA[1][c2].s, VF.s, oacc[1][dt]);
        }
      }
    }
  }
  u16* aop = ao4 + (size_t)br * brAo + (size_t)sp * 2097152;
  const int b = bh >> 3, h = bh & 7;
#pragma unroll
  for (int qh = 0; qh < 2; qh++)
#pragma unroll
    for (int dt = 0; dt < 2; dt++)
#pragma unroll
      for (int r = 0; r < 16; r++) {
        int qrow = qb * 256 + wid * 64 + qh * 32 + (r & 3) + 8 * (r >> 2) + 4 * hi;
        aop[(size_t)(b * 2048 + qrow) * 512 + h * 64 + dt * 32 + l31] = f2bf(oacc[qh][dt][r]);
      }
}

// ----------------------------------------------------------------
extern "C" void kernel_launch(void* const* d_in, const int* in_sizes, int n_in,
                              void* d_out, int out_size, void* d_ws, size_t ws_size,
                              hipStream_t stream) {
  const float* X[3] = {(const float*)d_in[0], (const float*)d_in[1], (const float*)d_in[2]};
  const float* G1[3] = {(const float*)d_in[3], (const float*)d_in[9], (const float*)d_in[15]};
  const float* B1[3] = {(const float*)d_in[4], (const float*)d_in[10], (const float*)d_in[16]};
  const float* WQKV[3] = {(const float*)d_in[5], (const float*)d_in[11], (const float*)d_in[17]};
  const float* RMS[3] = {(const float*)d_in[6], (const float*)d_in[12], (const float*)d_in[18]};
  const float* WO[3] = {(const float*)d_in[7], (const float*)d_in[13], (const float*)d_in[19]};
  const float* BO[3] = {(const float*)d_in[8], (const float*)d_in[14], (const float*)d_in[20]};
  const float* G2 = (const float*)d_in[21];
  const float* B2 = (const float*)d_in[22];
  const float* WFC1 = (const float*)d_in[23];
  const float* BFC1 = (const float*)d_in[24];
  const float* WFC2 = (const float*)d_in[25];
  const float* BFC2 = (const float*)d_in[26];
  float* dout = (float*)d_out;
  u16* W = (u16*)d_ws;

  const bool batched = ws_size >= 88080384ULL;  // 44,040,192 u16 elems

  // 1) all weight transposes, one launch (shared)
  u16* wqkvT = W;            // [3][1536][256]
  u16* woT = W + 1179648;    // [3][256][512]
  u16* fc1T = W + 1572864;   // [1024][768]
  u16* fc2T = W + 2359296;   // [768][1024]
  u16* xn = W + 3145728;     // [3][4096][256]   .. 6,291,456
  TrArgs ta;
  const float* srcs[8] = {WQKV[0], WQKV[1], WQKV[2], WO[0], WO[1], WO[2], WFC1, WFC2};
  u16* dsts[8] = {wqkvT, wqkvT + 393216, wqkvT + 786432, woT, woT + 131072, woT + 262144, fc1T, fc2T};
  int Ks_[8] = {256, 256, 256, 512, 512, 512, 768, 1024};
  int Ns_[8] = {1536, 1536, 1536, 256, 256, 256, 1024, 768};
  int tst[9] = {0, 384, 768, 1152, 1280, 1408, 1536, 2304, 3072};
  for (int i = 0; i < 8; i++) {
    ta.src[i] = srcs[i];
    ta.dst[i] = dsts[i];
    ta.K[i] = Ks_[i];
    ta.N[i] = Ns_[i];
    ta.tstart[i] = tst[i];
  }
  ta.tstart[8] = tst[8];
  hipLaunchKernelGGL(tr_kernel, dim3(3072), dim3(256), 0, stream, ta);

  // 2) LN1 (shared)
  LN1Args la;
  for (int i = 0; i < 3; i++) {
    la.x[i] = X[i];
    la.g[i] = G1[i];
    la.b[i] = B1[i];
  }
  la.out = xn;
  hipLaunchKernelGGL(ln1_kernel, dim3(1024, 3), dim3(256), 0, stream, la);

  u16 *ln2b, *hbuf;

  if (batched) {
    u16* qall = W + 6291456;
    u16* kall = W + 12582912;
    u16* vall = W + 18874368;
    u16* ao4 = W + 25165824;   // [3][2][4096][512]
    u16* aoN = W + 37748736;   // [3][4096][512]
    ln2b = W + 6291456;
    hbuf = W + 9437184;

    GemmQkvArgs gq = {xn, wqkvT, qall, kall, vall};
    hipLaunchKernelGGL(gemmqkv_kernel, dim3(12, 32, 3), dim3(256), 0, stream, gq);

    hipLaunchKernelGGL((attn_kernel<2, 3>), dim3(768), dim3(256), 0, stream,
                       qall, kall, vall, ao4, 2097152, 4194304);

    RmsArgs ra;
    ra.ao4 = ao4;
    for (int i = 0; i < 3; i++) ra.sc[i] = RMS[i];
    ra.aoN = aoN;
    ra.brAo = 4194304;
    ra.brAoN = 2097152;
    hipLaunchKernelGGL(rms_sum_kernel<2>, dim3(1024, 3), dim3(256), 0, stream, ra);

    Gemm64Args gw;
    gw.A = aoN;
    gw.Bt = woT;
    for (int i = 0; i < 3; i++) {
      gw.bias[i] = BO[i];
      gw.res[i] = X[i];
    }
    gw.outf = dout;
    gw.aStr = 2097152;
    gw.btStr = 131072;
    gw.outStr = 1048576;
    hipLaunchKernelGGL(gemm64_kernel, dim3(4, 64, 3), dim3(256), 0, stream, gw);
  } else {
    // Serial fallback (peak 44 MiB)
    u16* qz = W + 6291456;
    u16* kz = W + 8388608;
    u16* vz = W + 10485760;
    u16* ao4 = W + 12582912;  // [4][4096][512]
    u16* aoN = W + 20971520;
    ln2b = W + 6291456;
    hbuf = W + 9437184;

    for (int z = 0; z < 3; z++) {
      GemmQkvArgs gq = {xn + (size_t)z * 1048576, wqkvT + (size_t)z * 393216, qz, kz, vz};
      hipLaunchKernelGGL(gemmqkv_kernel, dim3(12, 32, 1), dim3(256), 0, stream, gq);

      hipLaunchKernelGGL((attn_kernel<4, 1>), dim3(512), dim3(256), 0, stream,
                         qz, kz, vz, ao4, 0, 0);

      RmsArgs ra;
      ra.ao4 = ao4;
      ra.sc[0] = RMS[z];
      ra.sc[1] = RMS[z];
      ra.sc[2] = RMS[z];
      ra.aoN = aoN;
      ra.brAo = 0;
      ra.brAoN = 0;
      hipLaunchKernelGGL(rms_sum_kernel<4>, dim3(1024, 1), dim3(256), 0, stream, ra);

      Gemm64Args gw;
      gw.A = aoN;
      gw.Bt = woT + (size_t)z * 131072;
      for (int i = 0; i < 3; i++) {
        gw.bias[i] = BO[z];
        gw.res[i] = X[z];
      }
      gw.outf = dout + (size_t)z * 1048576;
      gw.aStr = 0;
      gw.btStr = 0;
      gw.outStr = 0;
      hipLaunchKernelGGL(gemm64_kernel, dim3(4, 64, 1), dim3(256), 0, stream, gw);
    }
  }

  // 4) LN2 -> bf16
  hipLaunchKernelGGL(ln2_kernel, dim3(1024), dim3(256), 0, stream, dout, G2, B2, ln2b);

  // 5) FC1 (M=4096,N=1024,K=768) + gelu -> hbuf
  GemmMlpArgs g1 = {};
  g1.A = ln2b;
  g1.Bt = fc1T;
  g1.K = 768;
  g1.bias = BFC1;
  g1.oh = hbuf;
  hipLaunchKernelGGL(gemmmlp_kernel<0>, dim3(16, 32), dim3(256), 0, stream, g1);

  // 6) FC2 (M=4096,N=768,K=1024) + bias + residual RMW on d_out
  GemmMlpArgs g2 = {};
  g2.A = hbuf;
  g2.Bt = fc2T;
  g2.K = 1024;
  g2.bias = BFC2;
  g2.outf = dout;
  hipLaunchKernelGGL(gemmmlp_kernel<1>, dim3(12, 32), dim3(256), 0, stream, g2);
}